// Round 1
// baseline (56.328 us; speedup 1.0000x reference)
//
#include <hip/hip_runtime.h>

// CompressImageGPU: fused bilinear down(0.5x, antialias) -> up -> +block noise -> clip.
// x: [32,3,512,512] f32, block_noise: [32,64,64] f32, out: [32,3,512,512] f32.
//
// Per-dim weights (jax.image.resize, half-pixel centers, antialias=True):
//  down k: taps x[2k-1..2k+2] w=(1/8,3/8,3/8,1/8); k=0 -> (0,3/7,3/7,1/7); k=255 mirrored
//  up   o even=2k: (0.25,0.75) over ds[k-1],ds[k]; odd: (0.75,0.25) over ds[k],ds[k+1];
//       o=0 / o=511 -> weight 1.0 on the single in-range tap.

namespace {
constexpr int IMG = 512;
constexpr int NDS = 256;     // downsampled dim
constexpr int TILE = 64;     // output tile (square)
constexpr int DST = TILE / 2 + 2;  // 34 ds values needed per tile dim
}

__device__ __forceinline__ void down_weights(int k, int& j0, float w[4]) {
  j0 = 2 * k - 1;
  w[0] = 0.125f; w[1] = 0.375f; w[2] = 0.375f; w[3] = 0.125f;
  if (k == 0)       { w[0] = 0.0f;        w[1] = 3.0f/7.0f; w[2] = 3.0f/7.0f; w[3] = 1.0f/7.0f; }
  if (k == NDS - 1) { w[0] = 1.0f/7.0f;   w[1] = 3.0f/7.0f; w[2] = 3.0f/7.0f; w[3] = 0.0f; }
}

__global__ __launch_bounds__(256) void compress_fused_kernel(
    const float* __restrict__ x, const float* __restrict__ bn,
    float* __restrict__ out) {
  const int tx = blockIdx.x;     // 0..7  (tile col)
  const int ty = blockIdx.y;     // 0..7  (tile row)
  const int plane = blockIdx.z;  // b*3 + c
  const int b = plane / 3;
  const int x0 = tx * TILE, y0 = ty * TILE;
  const int tid = threadIdx.x;

  __shared__ float ds[DST][DST + 2];  // 34x36 (pad to dodge stride conflicts)
  __shared__ float nz[64];            // 8x8 noise values for this tile

  const float* xp = x + (size_t)plane * (IMG * IMG);
  float* op = out + (size_t)plane * (IMG * IMG);

  // ---- noise staging: one value per 8x8 block of this tile ----
  if (tid < 64) {
    const int brow = (y0 >> 3) + (tid >> 3);
    const int bcol = (x0 >> 3) + (tid & 7);
    nz[tid] = (bn[(size_t)b * 4096 + brow * 64 + bcol] - 0.5f) / 50.0f;
  }

  // ---- stage 1: 34x34 ds tile from global x ----
  const int kyb = (y0 >> 1) - 1;
  const int kxb = (x0 >> 1) - 1;
  for (int p = tid; p < DST * DST; p += 256) {
    const int dy = p / DST;
    const int dx = p - dy * DST;
    int ky = kyb + dy; ky = max(0, min(NDS - 1, ky));
    int kx = kxb + dx; kx = max(0, min(NDS - 1, kx));
    int jy0, jx0;
    float wy[4], wx[4];
    down_weights(ky, jy0, wy);
    down_weights(kx, jx0, wx);
    float s = 0.0f;
#pragma unroll
    for (int a = 0; a < 4; ++a) {
      const int jy = max(0, min(IMG - 1, jy0 + a));
      const float* row = xp + (size_t)jy * IMG;
      float rs = 0.0f;
#pragma unroll
      for (int q = 0; q < 4; ++q) {
        const int jx = max(0, min(IMG - 1, jx0 + q));
        rs += wx[q] * row[jx];
      }
      s += wy[a] * rs;
    }
    ds[dy][dx] = s;
  }
  __syncthreads();

  // ---- stage 2: upsample + noise + clip, coalesced stores ----
  const int c = tid & 63;        // local col
  const int gx = x0 + c;
  int lx0, lx1;
  float ux0, ux1;
  {
    const int h = c >> 1;
    if (gx & 1) { lx0 = h + 1; lx1 = h + 2; ux0 = 0.75f; ux1 = 0.25f; }
    else        { lx0 = h;     lx1 = h + 1; ux0 = 0.25f; ux1 = 0.75f; }
    if (gx == 0)       { ux0 = 0.0f; ux1 = 1.0f; }
    if (gx == IMG - 1) { ux0 = 1.0f; ux1 = 0.0f; }
  }

#pragma unroll
  for (int i = 0; i < 16; ++i) {
    const int r = (tid >> 6) + 4 * i;  // wave w does rows w, w+4, ...
    const int gy = y0 + r;
    int ly0, ly1;
    float uy0, uy1;
    const int v = r >> 1;
    if (gy & 1) { ly0 = v + 1; ly1 = v + 2; uy0 = 0.75f; uy1 = 0.25f; }
    else        { ly0 = v;     ly1 = v + 1; uy0 = 0.25f; uy1 = 0.75f; }
    if (gy == 0)       { uy0 = 0.0f; uy1 = 1.0f; }
    if (gy == IMG - 1) { uy0 = 1.0f; uy1 = 0.0f; }

    const float r0 = ux0 * ds[ly0][lx0] + ux1 * ds[ly0][lx1];
    const float r1 = ux0 * ds[ly1][lx0] + ux1 * ds[ly1][lx1];
    float val = uy0 * r0 + uy1 * r1;
    val += nz[((r >> 3) << 3) + (c >> 3)];
    val = fminf(1.0f, fmaxf(-1.0f, val));
    op[(size_t)gy * IMG + gx] = val;
  }
}

extern "C" void kernel_launch(void* const* d_in, const int* in_sizes, int n_in,
                              void* d_out, int out_size, void* d_ws, size_t ws_size,
                              hipStream_t stream) {
  const float* x  = (const float*)d_in[0];
  const float* bn = (const float*)d_in[1];
  float* out = (float*)d_out;

  const int n_planes = in_sizes[0] / (IMG * IMG);  // B*C = 96
  dim3 grid(IMG / TILE, IMG / TILE, n_planes);     // (8, 8, 96)
  dim3 block(256);
  compress_fused_kernel<<<grid, block, 0, stream>>>(x, bn, out);
}

// Round 2
// 53.942 us; speedup vs baseline: 1.0442x; 1.0442x over previous
//
#include <hip/hip_runtime.h>

// CompressImageGPU: fused bilinear down(0.5x, antialias) -> up -> +block noise -> clip,
// algebraically composed into ONE separable 6-tap convolution on x.
//
// Per dim, interior: out[o] = conv(x, w)/32 with
//   even o: taps o-3..o+2, w=(1,3,6,10,9,3)/32
//   odd  o: taps o-2..o+3, w=(3,9,10,6,3,1)/32
// Boundary indices 0,1,2 and 509,510,511 get composed weights from the
// renormalized down-edge (3/7,3/7,1/7) and degenerate up-edge (weight 1).

namespace {
constexpr int IMG = 512;
constexpr int TILE = 64;
constexpr int HROWS = TILE + 6;  // 70 h-pass rows (halo 3 top, 3 bottom)
}

// Composite 1D weights: out1d[o] = sum_t w[t] * x[p0 + t], p0 returned (0..506).
__device__ __forceinline__ int comp_weights(int o, float w[6]) {
  constexpr float i32 = 1.0f / 32.0f;
  if (o >= 3 && o <= IMG - 4) {
    if (o & 1) {
      w[0] = 3*i32; w[1] = 9*i32; w[2] = 10*i32; w[3] = 6*i32; w[4] = 3*i32; w[5] = 1*i32;
      return o - 2;
    } else {
      w[0] = 1*i32; w[1] = 3*i32; w[2] = 6*i32; w[3] = 10*i32; w[4] = 9*i32; w[5] = 3*i32;
      return o - 3;
    }
  }
  constexpr float i7 = 1.0f / 7.0f;
  constexpr float i28 = 1.0f / 28.0f;
  switch (o) {
    case 0:
      w[0] = 3*i7; w[1] = 3*i7; w[2] = 1*i7; w[3] = 0.0f; w[4] = 0.0f; w[5] = 0.0f;
      return 0;
    case 1:
      w[0] = 9*i28; w[1] = 9*i28 + 1*i32; w[2] = 3*i28 + 3*i32;
      w[3] = 3*i32; w[4] = 1*i32; w[5] = 0.0f;
      return 0;
    case 2:
      w[0] = 3*i28; w[1] = 3*i28 + 3*i32; w[2] = 1*i28 + 9*i32;
      w[3] = 9*i32; w[4] = 3*i32; w[5] = 0.0f;
      return 0;
    case IMG - 3:  // 509  (mirror of 2)
      w[0] = 0.0f; w[1] = 3*i32; w[2] = 9*i32;
      w[3] = 1*i28 + 9*i32; w[4] = 3*i28 + 3*i32; w[5] = 3*i28;
      return IMG - 6;
    case IMG - 2:  // 510  (mirror of 1)
      w[0] = 0.0f; w[1] = 1*i32; w[2] = 3*i32;
      w[3] = 3*i28 + 3*i32; w[4] = 9*i28 + 1*i32; w[5] = 9*i28;
      return IMG - 6;
    default:       // 511  (mirror of 0)
      w[0] = 0.0f; w[1] = 0.0f; w[2] = 0.0f;
      w[3] = 1*i7; w[4] = 3*i7; w[5] = 3*i7;
      return IMG - 6;
  }
}

__global__ __launch_bounds__(256) void compress_fused2_kernel(
    const float* __restrict__ x, const float* __restrict__ bn,
    float* __restrict__ out) {
  const int tx = blockIdx.x;     // tile col 0..7
  const int ty = blockIdx.y;     // tile row 0..7
  const int plane = blockIdx.z;  // b*3 + c
  const int b = plane / 3;
  const int x0 = tx * TILE, y0 = ty * TILE;
  const int tid = threadIdx.x;
  const int c  = tid & 63;       // lane column within tile
  const int rg = tid >> 6;       // row group 0..3
  const int gx = x0 + c;

  __shared__ float H[HROWS][TILE];  // h-pass results; col reads are lane-consecutive
  __shared__ float nz[64];          // 8x8 noise values for this tile

  const float* xp = x + (size_t)plane * (IMG * IMG);
  float* op = out + (size_t)plane * (IMG * IMG);

  // noise staging: one value per 8x8 block of this tile
  if (tid < 64) {
    const int brow = (y0 >> 3) + (tid >> 3);
    const int bcol = (x0 >> 3) + (tid & 7);
    nz[tid] = (bn[(size_t)b * 4096 + brow * 64 + bcol] - 0.5f) / 50.0f;
  }

  // column weights (fixed per thread)
  float wh[6];
  const int px = comp_weights(gx, wh);

  // ---- h-pass: rows y0-3 .. y0+66 (clamped), straight from global ----
  for (int r = rg; r < HROWS; r += 4) {
    int g = y0 - 3 + r;
    g = max(0, min(IMG - 1, g));
    const float* row = xp + (size_t)g * IMG + px;
    H[r][c] = wh[0] * row[0] + wh[1] * row[1] + wh[2] * row[2] +
              wh[3] * row[3] + wh[4] * row[4] + wh[5] * row[5];
  }
  __syncthreads();

  // ---- v-pass: 6 LDS taps + noise + clip, coalesced stores ----
#pragma unroll 4
  for (int i = 0; i < 16; ++i) {
    const int r = rg + 4 * i;    // output row within tile, 0..63
    const int gy = y0 + r;
    float wv[6];
    const int py = comp_weights(gy, wv);     // wave-uniform branch
    const int l = py - (y0 - 3);             // local base row in H
    float v = wv[0] * H[l    ][c] + wv[1] * H[l + 1][c] + wv[2] * H[l + 2][c] +
              wv[3] * H[l + 3][c] + wv[4] * H[l + 4][c] + wv[5] * H[l + 5][c];
    v += nz[((r >> 3) << 3) + (c >> 3)];
    v = fminf(1.0f, fmaxf(-1.0f, v));
    op[(size_t)gy * IMG + gx] = v;
  }
}

extern "C" void kernel_launch(void* const* d_in, const int* in_sizes, int n_in,
                              void* d_out, int out_size, void* d_ws, size_t ws_size,
                              hipStream_t stream) {
  const float* x  = (const float*)d_in[0];
  const float* bn = (const float*)d_in[1];
  float* out = (float*)d_out;

  const int n_planes = in_sizes[0] / (IMG * IMG);  // B*C = 96
  dim3 grid(IMG / TILE, IMG / TILE, n_planes);     // (8, 8, 96)
  dim3 block(256);
  compress_fused2_kernel<<<grid, block, 0, stream>>>(x, bn, out);
}

// Round 3
// 50.113 us; speedup vs baseline: 1.1240x; 1.0764x over previous
//
#include <hip/hip_runtime.h>

// CompressImageGPU: bilinear down(0.5, antialias) -> up -> +8x8 block noise -> clip,
// composed into one separable 6-tap conv. Fully float4-vectorized: each thread
// owns 4 consecutive output cols; v-pass produces 4 consecutive rows from a
// 10-row register window (constant indices everywhere).
//
// Interior 1-D weights: even o: taps o-3..o+2, (1,3,6,10,9,3)/32
//                       odd  o: taps o-2..o+3, (3,9,10,6,3,1)/32
// Edges (o=0,1,2,509,510,511): composed from renormalized down-edge + degenerate up.

namespace {
constexpr int IMG = 512;
constexpr int TILE = 64;
constexpr int HROWS = TILE + 6;  // 70
constexpr float I32 = 1.0f / 32.0f;
constexpr float I7  = 1.0f / 7.0f;
constexpr float I28 = 1.0f / 28.0f;
}

__device__ __forceinline__ float4 f4fma(float w, float4 a, float4 acc) {
  acc.x = fmaf(w, a.x, acc.x); acc.y = fmaf(w, a.y, acc.y);
  acc.z = fmaf(w, a.z, acc.z); acc.w = fmaf(w, a.w, acc.w);
  return acc;
}
__device__ __forceinline__ float4 f4mul(float w, float4 a) {
  return make_float4(w * a.x, w * a.y, w * a.z, w * a.w);
}

__global__ __launch_bounds__(256) void compress_fused3_kernel(
    const float* __restrict__ x, const float* __restrict__ bn,
    float* __restrict__ out) {
  const int tx = blockIdx.x, ty = blockIdx.y, plane = blockIdx.z;
  const int b = plane / 3;
  const int x0 = tx * TILE, y0 = ty * TILE;
  const int tid = threadIdx.x;
  const int cg = tid & 15;   // column group: output cols gx0..gx0+3
  const int rs = tid >> 4;   // row slot 0..15
  const int gx0 = x0 + 4 * cg;

  __shared__ float H[HROWS][TILE];  // h-pass results
  __shared__ float nz[64];          // 8x8 noise for this tile

  const float* xp = x + (size_t)plane * (IMG * IMG);
  float* op = out + (size_t)plane * (IMG * IMG);

  if (tid < 64) {
    const int brow = (y0 >> 3) + (tid >> 3);
    const int bcol = (x0 >> 3) + (tid & 7);
    nz[tid] = (bn[(size_t)b * 4096 + brow * 64 + bcol] - 0.5f) * 0.02f;
  }

  const bool left  = (gx0 == 0);
  const bool right = (gx0 == IMG - 4);
  const int A0 = left ? 0 : (right ? IMG - 12 : gx0 - 4);  // f[i] = x[A0+i]

  // ---- h-pass: rows y0-3 .. y0+66 (clamped), 4 cols per thread ----
#pragma unroll
  for (int k = 0; k < 5; ++k) {
    const int r = rs + 16 * k;
    if (r < HROWS) {
      int g = y0 - 3 + r;
      g = max(0, min(IMG - 1, g));
      const float* row = xp + (size_t)g * IMG + A0;
      const float4 qa = *(const float4*)(row);
      const float4 qb = *(const float4*)(row + 4);
      const float4 qc = *(const float4*)(row + 8);
      const float f0 = qa.x, f1 = qa.y, f2 = qa.z, f3 = qa.w;
      const float f4_ = qb.x, f5 = qb.y, f6 = qb.z, f7 = qb.w;
      const float f8 = qc.x, f9 = qc.y, f10 = qc.z, f11 = qc.w;
      float4 h;
      if (left) {  // f[i] = x[i]
        h.x = (3.f * f0 + 3.f * f1 + f2) * I7;
        h.y = 9*I28*f0 + (9*I28 + I32)*f1 + (3*I28 + 3*I32)*f2 + 3*I32*f3 + I32*f4_;
        h.z = 3*I28*f0 + (3*I28 + 3*I32)*f1 + (I28 + 9*I32)*f2 + 9*I32*f3 + 3*I32*f4_;
        h.w = (3.f*f1 + 9.f*f2 + 10.f*f3 + 6.f*f4_ + 3.f*f5 + f6) * I32;
      } else if (right) {  // f[i] = x[500+i]
        h.x = (f5 + 3.f*f6 + 6.f*f7 + 10.f*f8 + 9.f*f9 + 3.f*f10) * I32;
        h.y = 3*I32*f7 + 9*I32*f8 + (I28 + 9*I32)*f9 + (3*I28 + 3*I32)*f10 + 3*I28*f11;
        h.z = I32*f7 + 3*I32*f8 + (3*I28 + 3*I32)*f9 + (9*I28 + I32)*f10 + 9*I28*f11;
        h.w = (f9 + 3.f*f10 + 3.f*f11) * I7;
      } else {  // f[i] = x[gx0-4+i]
        h.x = (f1 + 3.f*f2 + 6.f*f3 + 10.f*f4_ + 9.f*f5 + 3.f*f6) * I32;
        h.y = (3.f*f3 + 9.f*f4_ + 10.f*f5 + 6.f*f6 + 3.f*f7 + f8) * I32;
        h.z = (f3 + 3.f*f4_ + 6.f*f5 + 10.f*f6 + 9.f*f7 + 3.f*f8) * I32;
        h.w = (3.f*f5 + 9.f*f6 + 10.f*f7 + 6.f*f8 + 3.f*f9 + f10) * I32;
      }
      *(float4*)&H[r][4 * cg] = h;
    }
  }
  __syncthreads();

  // ---- v-pass: 4 consecutive output rows per thread from 10-row window ----
  const int wb = 4 * rs;  // window base: H rows wb..wb+9 (global rows y0+wb-3 ..)
  const float4 q0 = *(const float4*)&H[wb + 0][4 * cg];
  const float4 q1 = *(const float4*)&H[wb + 1][4 * cg];
  const float4 q2 = *(const float4*)&H[wb + 2][4 * cg];
  const float4 q3 = *(const float4*)&H[wb + 3][4 * cg];
  const float4 q4 = *(const float4*)&H[wb + 4][4 * cg];
  const float4 q5 = *(const float4*)&H[wb + 5][4 * cg];
  const float4 q6 = *(const float4*)&H[wb + 6][4 * cg];
  const float4 q7 = *(const float4*)&H[wb + 7][4 * cg];
  const float4 q8 = *(const float4*)&H[wb + 8][4 * cg];
  const float4 q9 = *(const float4*)&H[wb + 9][4 * cg];

  const float nzv = nz[(rs >> 1) * 8 + (cg >> 1)];
  const bool top = (y0 == 0 && rs == 0);
  const bool bot = (y0 == IMG - TILE && rs == 15);

  float4 o0, o1, o2, o3;
  if (top) {
    // H[0..3] all = row 0. gy=0,1,2 edge; gy=3 odd-interior (taps rows 1..6 = q4..q9)
    o0 = f4fma(3*I7, q3, f4fma(3*I7, q4, f4mul(I7, q5)));
    o1 = f4fma(9*I28, q3, f4fma(9*I28 + I32, q4,
         f4fma(3*I28 + 3*I32, q5, f4fma(3*I32, q6, f4mul(I32, q7)))));
    o2 = f4fma(3*I28, q3, f4fma(3*I28 + 3*I32, q4,
         f4fma(I28 + 9*I32, q5, f4fma(9*I32, q6, f4mul(3*I32, q7)))));
    o3 = f4fma(3*I32, q4, f4fma(9*I32, q5, f4fma(10*I32, q6,
         f4fma(6*I32, q7, f4fma(3*I32, q8, f4mul(I32, q9))))));
  } else if (bot) {
    // q0 = H[60] = global row 505; gy=508 interior-even(idx0); 509,510,511 edge
    o0 = f4fma(I32, q0, f4fma(3*I32, q1, f4fma(6*I32, q2,
         f4fma(10*I32, q3, f4fma(9*I32, q4, f4mul(3*I32, q5))))));
    o1 = f4fma(3*I32, q2, f4fma(9*I32, q3, f4fma(I28 + 9*I32, q4,
         f4fma(3*I28 + 3*I32, q5, f4mul(3*I28, q6)))));
    o2 = f4fma(I32, q2, f4fma(3*I32, q3, f4fma(3*I28 + 3*I32, q4,
         f4fma(9*I28 + I32, q5, f4mul(9*I28, q6)))));
    o3 = f4fma(I7, q4, f4fma(3*I7, q5, f4mul(3*I7, q6)));
  } else {
    // gy = y0+4rs+ii; parity(gy) = parity(ii); idx = (0,2,2,4)
    o0 = f4fma(I32, q0, f4fma(3*I32, q1, f4fma(6*I32, q2,
         f4fma(10*I32, q3, f4fma(9*I32, q4, f4mul(3*I32, q5))))));
    o1 = f4fma(3*I32, q2, f4fma(9*I32, q3, f4fma(10*I32, q4,
         f4fma(6*I32, q5, f4fma(3*I32, q6, f4mul(I32, q7))))));
    o2 = f4fma(I32, q2, f4fma(3*I32, q3, f4fma(6*I32, q4,
         f4fma(10*I32, q5, f4fma(9*I32, q6, f4mul(3*I32, q7))))));
    o3 = f4fma(3*I32, q4, f4fma(9*I32, q5, f4fma(10*I32, q6,
         f4fma(6*I32, q7, f4fma(3*I32, q8, f4mul(I32, q9))))));
  }

  const int gy0 = y0 + 4 * rs;
#define FINISH_STORE(o, ii)                                                    \
  {                                                                            \
    float4 v = o;                                                              \
    v.x = fminf(1.f, fmaxf(-1.f, v.x + nzv));                                  \
    v.y = fminf(1.f, fmaxf(-1.f, v.y + nzv));                                  \
    v.z = fminf(1.f, fmaxf(-1.f, v.z + nzv));                                  \
    v.w = fminf(1.f, fmaxf(-1.f, v.w + nzv));                                  \
    *(float4*)(op + (size_t)(gy0 + ii) * IMG + gx0) = v;                       \
  }
  FINISH_STORE(o0, 0)
  FINISH_STORE(o1, 1)
  FINISH_STORE(o2, 2)
  FINISH_STORE(o3, 3)
#undef FINISH_STORE
}

extern "C" void kernel_launch(void* const* d_in, const int* in_sizes, int n_in,
                              void* d_out, int out_size, void* d_ws, size_t ws_size,
                              hipStream_t stream) {
  const float* x  = (const float*)d_in[0];
  const float* bn = (const float*)d_in[1];
  float* out = (float*)d_out;

  const int n_planes = in_sizes[0] / (IMG * IMG);  // B*C = 96
  dim3 grid(IMG / TILE, IMG / TILE, n_planes);     // (8, 8, 96)
  dim3 block(256);
  compress_fused3_kernel<<<grid, block, 0, stream>>>(x, bn, out);
}

// Round 4
// 48.619 us; speedup vs baseline: 1.1586x; 1.0307x over previous
//
#include <hip/hip_runtime.h>

// CompressImageGPU: bilinear down(0.5, antialias) -> up -> +8x8 block noise -> clip,
// composed into one separable 6-tap conv on x.
// Round 4: 2-deep pipelined global loads in h-pass (6 dwordx4 in flight/wave),
// non-temporal output stores, chunked v-pass windows to keep VGPR <= 64.

typedef float f32x4 __attribute__((ext_vector_type(4)));

namespace {
constexpr int IMG = 512;
constexpr int TILE = 64;
constexpr int HROWS = TILE + 6;  // 70
constexpr float I32 = 1.0f / 32.0f;
constexpr float I7  = 1.0f / 7.0f;
constexpr float I28 = 1.0f / 28.0f;
}

__device__ __forceinline__ f32x4 vfma(float w, f32x4 a, f32x4 acc) {
  acc.x = fmaf(w, a.x, acc.x); acc.y = fmaf(w, a.y, acc.y);
  acc.z = fmaf(w, a.z, acc.z); acc.w = fmaf(w, a.w, acc.w);
  return acc;
}
__device__ __forceinline__ f32x4 vmul(float w, f32x4 a) {
  f32x4 r; r.x = w * a.x; r.y = w * a.y; r.z = w * a.z; r.w = w * a.w;
  return r;
}

__global__ __launch_bounds__(256) void compress_fused4_kernel(
    const float* __restrict__ x, const float* __restrict__ bn,
    float* __restrict__ out) {
  const int tx = blockIdx.x, ty = blockIdx.y, plane = blockIdx.z;
  const int b = plane / 3;
  const int x0 = tx * TILE, y0 = ty * TILE;
  const int tid = threadIdx.x;
  const int cg = tid & 15;   // column group: output cols gx0..gx0+3
  const int rs = tid >> 4;   // row slot 0..15
  const int gx0 = x0 + 4 * cg;

  __shared__ float H[HROWS][TILE];
  __shared__ float nz[64];

  const float* xp = x + (size_t)plane * (IMG * IMG);
  float* op = out + (size_t)plane * (IMG * IMG);

  if (tid < 64) {
    const int brow = (y0 >> 3) + (tid >> 3);
    const int bcol = (x0 >> 3) + (tid & 7);
    nz[tid] = (bn[(size_t)b * 4096 + brow * 64 + bcol] - 0.5f) * 0.02f;
  }

  const bool left  = (gx0 == 0);
  const bool right = (gx0 == IMG - 4);
  const int A0 = left ? 0 : (right ? IMG - 12 : gx0 - 4);  // f[i] = x[A0+i]

  auto rowptr = [&](int k) -> const f32x4* {
    int g = y0 - 3 + rs + 16 * k;
    g = max(0, min(IMG - 1, g));
    return (const f32x4*)(xp + (size_t)g * IMG + A0);
  };

  // ---- h-pass: 2-deep pipelined loads ----
  const f32x4* p0 = rowptr(0);
  f32x4 qa = p0[0], qb = p0[1], qc = p0[2];

#pragma unroll
  for (int k = 0; k < 5; ++k) {
    f32x4 na, nb, nc;
    if (k < 4) {
      const f32x4* p = rowptr(k + 1);
      na = p[0]; nb = p[1]; nc = p[2];
    }
    const int r = rs + 16 * k;
    if (r < HROWS) {
      const float f0 = qa.x, f1 = qa.y, f2 = qa.z, f3 = qa.w;
      const float f4_ = qb.x, f5 = qb.y, f6 = qb.z, f7 = qb.w;
      const float f8 = qc.x, f9 = qc.y, f10 = qc.z, f11 = qc.w;
      f32x4 h;
      if (left) {  // f[i] = x[i]
        h.x = (3.f * f0 + 3.f * f1 + f2) * I7;
        h.y = 9*I28*f0 + (9*I28 + I32)*f1 + (3*I28 + 3*I32)*f2 + 3*I32*f3 + I32*f4_;
        h.z = 3*I28*f0 + (3*I28 + 3*I32)*f1 + (I28 + 9*I32)*f2 + 9*I32*f3 + 3*I32*f4_;
        h.w = (3.f*f1 + 9.f*f2 + 10.f*f3 + 6.f*f4_ + 3.f*f5 + f6) * I32;
      } else if (right) {  // f[i] = x[500+i]
        h.x = (f5 + 3.f*f6 + 6.f*f7 + 10.f*f8 + 9.f*f9 + 3.f*f10) * I32;
        h.y = 3*I32*f7 + 9*I32*f8 + (I28 + 9*I32)*f9 + (3*I28 + 3*I32)*f10 + 3*I28*f11;
        h.z = I32*f7 + 3*I32*f8 + (3*I28 + 3*I32)*f9 + (9*I28 + I32)*f10 + 9*I28*f11;
        h.w = (f9 + 3.f*f10 + 3.f*f11) * I7;
      } else {  // f[i] = x[gx0-4+i]
        h.x = (f1 + 3.f*f2 + 6.f*f3 + 10.f*f4_ + 9.f*f5 + 3.f*f6) * I32;
        h.y = (3.f*f3 + 9.f*f4_ + 10.f*f5 + 6.f*f6 + 3.f*f7 + f8) * I32;
        h.z = (f3 + 3.f*f4_ + 6.f*f5 + 10.f*f6 + 9.f*f7 + 3.f*f8) * I32;
        h.w = (3.f*f5 + 9.f*f6 + 10.f*f7 + 6.f*f8 + 3.f*f9 + f10) * I32;
      }
      *(f32x4*)&H[r][4 * cg] = h;
    }
    if (k < 4) { qa = na; qb = nb; qc = nc; }
  }
  __syncthreads();

  // ---- v-pass: chunked 10-row window, NT stores ----
  const int wb = 4 * rs;  // H rows wb..wb+9
  const float nzv = nz[(rs >> 1) * 8 + (cg >> 1)];
  const bool top = (y0 == 0 && rs == 0);
  const bool bot = (y0 == IMG - TILE && rs == 15);
  const int gy0 = y0 + 4 * rs;

#define LDQ(j) (*(const f32x4*)&H[wb + (j)][4 * cg])
#define FINISH_STORE(o, ii)                                                    \
  {                                                                            \
    f32x4 v = o;                                                               \
    v.x = fminf(1.f, fmaxf(-1.f, v.x + nzv));                                  \
    v.y = fminf(1.f, fmaxf(-1.f, v.y + nzv));                                  \
    v.z = fminf(1.f, fmaxf(-1.f, v.z + nzv));                                  \
    v.w = fminf(1.f, fmaxf(-1.f, v.w + nzv));                                  \
    __builtin_nontemporal_store(v, (f32x4*)(op + (size_t)(gy0 + ii) * IMG + gx0)); \
  }

  const f32x4 q0 = LDQ(0), q1 = LDQ(1), q2 = LDQ(2);
  const f32x4 q3 = LDQ(3), q4 = LDQ(4), q5 = LDQ(5);

  f32x4 o0;
  if (top) {
    o0 = vfma(3*I7, q3, vfma(3*I7, q4, vmul(I7, q5)));
  } else if (bot) {
    o0 = vfma(I32, q0, vfma(3*I32, q1, vfma(6*I32, q2,
         vfma(10*I32, q3, vfma(9*I32, q4, vmul(3*I32, q5))))));
  } else {
    o0 = vfma(I32, q0, vfma(3*I32, q1, vfma(6*I32, q2,
         vfma(10*I32, q3, vfma(9*I32, q4, vmul(3*I32, q5))))));
  }
  FINISH_STORE(o0, 0)

  const f32x4 q6 = LDQ(6), q7 = LDQ(7);
  f32x4 o1, o2;
  if (top) {
    o1 = vfma(9*I28, q3, vfma(9*I28 + I32, q4,
         vfma(3*I28 + 3*I32, q5, vfma(3*I32, q6, vmul(I32, q7)))));
    o2 = vfma(3*I28, q3, vfma(3*I28 + 3*I32, q4,
         vfma(I28 + 9*I32, q5, vfma(9*I32, q6, vmul(3*I32, q7)))));
  } else if (bot) {
    o1 = vfma(3*I32, q2, vfma(9*I32, q3, vfma(I28 + 9*I32, q4,
         vfma(3*I28 + 3*I32, q5, vmul(3*I28, q6)))));
    o2 = vfma(I32, q2, vfma(3*I32, q3, vfma(3*I28 + 3*I32, q4,
         vfma(9*I28 + I32, q5, vmul(9*I28, q6)))));
  } else {
    o1 = vfma(3*I32, q2, vfma(9*I32, q3, vfma(10*I32, q4,
         vfma(6*I32, q5, vfma(3*I32, q6, vmul(I32, q7))))));
    o2 = vfma(I32, q2, vfma(3*I32, q3, vfma(6*I32, q4,
         vfma(10*I32, q5, vfma(9*I32, q6, vmul(3*I32, q7))))));
  }
  FINISH_STORE(o1, 1)
  FINISH_STORE(o2, 2)

  const f32x4 q8 = LDQ(8), q9 = LDQ(9);
  f32x4 o3;
  if (top) {
    o3 = vfma(3*I32, q4, vfma(9*I32, q5, vfma(10*I32, q6,
         vfma(6*I32, q7, vfma(3*I32, q8, vmul(I32, q9))))));
  } else if (bot) {
    o3 = vfma(I7, q4, vfma(3*I7, q5, vmul(3*I7, q6)));
  } else {
    o3 = vfma(3*I32, q4, vfma(9*I32, q5, vfma(10*I32, q6,
         vfma(6*I32, q7, vfma(3*I32, q8, vmul(I32, q9))))));
  }
  FINISH_STORE(o3, 3)
#undef FINISH_STORE
#undef LDQ
}

extern "C" void kernel_launch(void* const* d_in, const int* in_sizes, int n_in,
                              void* d_out, int out_size, void* d_ws, size_t ws_size,
                              hipStream_t stream) {
  const float* x  = (const float*)d_in[0];
  const float* bn = (const float*)d_in[1];
  float* out = (float*)d_out;

  const int n_planes = in_sizes[0] / (IMG * IMG);  // B*C = 96
  dim3 grid(IMG / TILE, IMG / TILE, n_planes);     // (8, 8, 96)
  dim3 block(256);
  compress_fused4_kernel<<<grid, block, 0, stream>>>(x, bn, out);
}

// Round 5
// 35.970 us; speedup vs baseline: 1.5660x; 1.3516x over previous
//
#include <hip/hip_runtime.h>

// CompressImageGPU: bilinear down(0.5, antialias) -> up -> +8x8 block noise -> clip,
// composed into one separable 6-tap conv on x.
// Round 5: full-width tiles (512x16) so every HBM read/write is a contiguous 2KB
// row (DRAM-burst friendly); 512-thread blocks; XCD-chunked block swizzle;
// 2-deep pipelined loads; NT stores.

typedef float f32x4 __attribute__((ext_vector_type(4)));

namespace {
constexpr int IMG = 512;
constexpr int TY = 16;          // output rows per block
constexpr int HROWS = TY + 6;   // 22
constexpr float I32 = 1.0f / 32.0f;
constexpr float I7  = 1.0f / 7.0f;
constexpr float I28 = 1.0f / 28.0f;
}

__device__ __forceinline__ f32x4 vfma(float w, f32x4 a, f32x4 acc) {
  acc.x = fmaf(w, a.x, acc.x); acc.y = fmaf(w, a.y, acc.y);
  acc.z = fmaf(w, a.z, acc.z); acc.w = fmaf(w, a.w, acc.w);
  return acc;
}
__device__ __forceinline__ f32x4 vmul(float w, f32x4 a) {
  f32x4 r; r.x = w * a.x; r.y = w * a.y; r.z = w * a.z; r.w = w * a.w;
  return r;
}

__global__ __launch_bounds__(512) void compress_fused5_kernel(
    const float* __restrict__ x, const float* __restrict__ bn,
    float* __restrict__ out) {
  // XCD-chunked bijective swizzle (nwg % 8 == 0): each XCD gets a contiguous
  // run of y-tiles so halo rows hit the same L2.
  const int nwg = gridDim.x;
  const int cpx = nwg >> 3;
  const int bid = blockIdx.x;
  const int logical = (bid & 7) * cpx + (bid >> 3);
  const int ty = logical & 31;      // y-tile 0..31
  const int plane = logical >> 5;   // 0..95
  const int b = plane / 3;
  const int y0 = ty * TY;
  const int tid = threadIdx.x;
  const int cg = tid & 127;         // column group: cols 4cg..4cg+3
  const int ts = tid >> 7;          // row slot 0..3
  const int gx0 = 4 * cg;

  __shared__ float H[HROWS][IMG];   // h-pass results (full width)
  __shared__ float nz[128];         // 64 x-blocks x 2 y-blocks noise

  const float* xp = x + (size_t)plane * (IMG * IMG);
  float* op = out + (size_t)plane * (IMG * IMG);

  if (tid < 128) {
    const int brow = (y0 >> 3) + (tid >> 6);
    const int bcol = tid & 63;
    nz[tid] = (bn[(size_t)b * 4096 + brow * 64 + bcol] - 0.5f) * 0.02f;
  }

  const bool left  = (cg == 0);
  const bool right = (cg == 127);
  const int A0 = left ? 0 : (right ? IMG - 12 : gx0 - 4);  // f[i] = x[A0+i]

  auto rowptr = [&](int r) -> const f32x4* {
    int g = y0 - 3 + r;
    g = max(0, min(IMG - 1, g));
    return (const f32x4*)(xp + (size_t)g * IMG + A0);
  };

  // ---- h-pass: rows ts, ts+4, ..., 2-deep pipelined loads ----
  f32x4 qa, qb, qc;
  { const f32x4* p = rowptr(ts); qa = p[0]; qb = p[1]; qc = p[2]; }

#pragma unroll
  for (int k = 0; k < 6; ++k) {
    const int r = ts + 4 * k;
    const int rn = r + 4;
    f32x4 na, nb, nc;
    if (rn < HROWS) { const f32x4* p = rowptr(rn); na = p[0]; nb = p[1]; nc = p[2]; }
    if (r < HROWS) {
      const float f0 = qa.x, f1 = qa.y, f2 = qa.z, f3 = qa.w;
      const float f4_ = qb.x, f5 = qb.y, f6 = qb.z, f7 = qb.w;
      const float f8 = qc.x, f9 = qc.y, f10 = qc.z, f11 = qc.w;
      f32x4 h;
      if (left) {  // f[i] = x[i]
        h.x = (3.f * f0 + 3.f * f1 + f2) * I7;
        h.y = 9*I28*f0 + (9*I28 + I32)*f1 + (3*I28 + 3*I32)*f2 + 3*I32*f3 + I32*f4_;
        h.z = 3*I28*f0 + (3*I28 + 3*I32)*f1 + (I28 + 9*I32)*f2 + 9*I32*f3 + 3*I32*f4_;
        h.w = (3.f*f1 + 9.f*f2 + 10.f*f3 + 6.f*f4_ + 3.f*f5 + f6) * I32;
      } else if (right) {  // f[i] = x[500+i]
        h.x = (f5 + 3.f*f6 + 6.f*f7 + 10.f*f8 + 9.f*f9 + 3.f*f10) * I32;
        h.y = 3*I32*f7 + 9*I32*f8 + (I28 + 9*I32)*f9 + (3*I28 + 3*I32)*f10 + 3*I28*f11;
        h.z = I32*f7 + 3*I32*f8 + (3*I28 + 3*I32)*f9 + (9*I28 + I32)*f10 + 9*I28*f11;
        h.w = (f9 + 3.f*f10 + 3.f*f11) * I7;
      } else {  // f[i] = x[gx0-4+i]
        h.x = (f1 + 3.f*f2 + 6.f*f3 + 10.f*f4_ + 9.f*f5 + 3.f*f6) * I32;
        h.y = (3.f*f3 + 9.f*f4_ + 10.f*f5 + 6.f*f6 + 3.f*f7 + f8) * I32;
        h.z = (f3 + 3.f*f4_ + 6.f*f5 + 10.f*f6 + 9.f*f7 + 3.f*f8) * I32;
        h.w = (3.f*f5 + 9.f*f6 + 10.f*f7 + 6.f*f8 + 3.f*f9 + f10) * I32;
      }
      *(f32x4*)&H[r][gx0] = h;
    }
    if (rn < HROWS) { qa = na; qb = nb; qc = nc; }
  }
  __syncthreads();

  // ---- v-pass: 4 consecutive output rows per thread from 10-row window ----
  const int wb = 4 * ts;  // H rows wb..wb+9
  const float nzv = nz[((ts >> 1) << 6) + (cg >> 1)];
  const bool top = (y0 == 0 && ts == 0);
  const bool bot = (y0 == IMG - TY && ts == 3);
  const int gy0 = y0 + 4 * ts;

#define LDQ(j) (*(const f32x4*)&H[wb + (j)][gx0])
#define FINISH_STORE(o, ii)                                                    \
  {                                                                            \
    f32x4 v = o;                                                               \
    v.x = fminf(1.f, fmaxf(-1.f, v.x + nzv));                                  \
    v.y = fminf(1.f, fmaxf(-1.f, v.y + nzv));                                  \
    v.z = fminf(1.f, fmaxf(-1.f, v.z + nzv));                                  \
    v.w = fminf(1.f, fmaxf(-1.f, v.w + nzv));                                  \
    __builtin_nontemporal_store(v, (f32x4*)(op + (size_t)(gy0 + ii) * IMG + gx0)); \
  }

  const f32x4 q0 = LDQ(0), q1 = LDQ(1), q2 = LDQ(2);
  const f32x4 q3 = LDQ(3), q4 = LDQ(4), q5 = LDQ(5);

  f32x4 o0;
  if (top) {
    o0 = vfma(3*I7, q3, vfma(3*I7, q4, vmul(I7, q5)));
  } else {
    o0 = vfma(I32, q0, vfma(3*I32, q1, vfma(6*I32, q2,
         vfma(10*I32, q3, vfma(9*I32, q4, vmul(3*I32, q5))))));
  }
  FINISH_STORE(o0, 0)

  const f32x4 q6 = LDQ(6), q7 = LDQ(7);
  f32x4 o1, o2;
  if (top) {
    o1 = vfma(9*I28, q3, vfma(9*I28 + I32, q4,
         vfma(3*I28 + 3*I32, q5, vfma(3*I32, q6, vmul(I32, q7)))));
    o2 = vfma(3*I28, q3, vfma(3*I28 + 3*I32, q4,
         vfma(I28 + 9*I32, q5, vfma(9*I32, q6, vmul(3*I32, q7)))));
  } else if (bot) {
    o1 = vfma(3*I32, q2, vfma(9*I32, q3, vfma(I28 + 9*I32, q4,
         vfma(3*I28 + 3*I32, q5, vmul(3*I28, q6)))));
    o2 = vfma(I32, q2, vfma(3*I32, q3, vfma(3*I28 + 3*I32, q4,
         vfma(9*I28 + I32, q5, vmul(9*I28, q6)))));
  } else {
    o1 = vfma(3*I32, q2, vfma(9*I32, q3, vfma(10*I32, q4,
         vfma(6*I32, q5, vfma(3*I32, q6, vmul(I32, q7))))));
    o2 = vfma(I32, q2, vfma(3*I32, q3, vfma(6*I32, q4,
         vfma(10*I32, q5, vfma(9*I32, q6, vmul(3*I32, q7))))));
  }
  FINISH_STORE(o1, 1)
  FINISH_STORE(o2, 2)

  const f32x4 q8 = LDQ(8), q9 = LDQ(9);
  f32x4 o3;
  if (bot) {
    o3 = vfma(I7, q4, vfma(3*I7, q5, vmul(3*I7, q6)));
  } else {
    o3 = vfma(3*I32, q4, vfma(9*I32, q5, vfma(10*I32, q6,
         vfma(6*I32, q7, vfma(3*I32, q8, vmul(I32, q9))))));
  }
  FINISH_STORE(o3, 3)
#undef FINISH_STORE
#undef LDQ
}

extern "C" void kernel_launch(void* const* d_in, const int* in_sizes, int n_in,
                              void* d_out, int out_size, void* d_ws, size_t ws_size,
                              hipStream_t stream) {
  const float* x  = (const float*)d_in[0];
  const float* bn = (const float*)d_in[1];
  float* out = (float*)d_out;

  const int n_planes = in_sizes[0] / (IMG * IMG);  // B*C = 96
  const int nwg = (IMG / TY) * n_planes;           // 32 * 96 = 3072 (div by 8)
  compress_fused5_kernel<<<dim3(nwg), dim3(512), 0, stream>>>(x, bn, out);
}